// Round 2
// 606.665 us; speedup vs baseline: 1.1671x; 1.1671x over previous
//
#include <hip/hip_runtime.h>

// ---- problem constants ----
#define BB 4
#define SS 1024
#define DD 1024
#define HH 16
#define DHH 64
#define DFF 4096
#define MROWS 4096   // B*S
#define NEG_BIG (-1e30f)
#define LOG2E 1.4426950408889634f
#define SCL_L2E 0.1803368801111244f   // 0.125 * log2(e)

typedef float  f32x4  __attribute__((ext_vector_type(4)));
typedef __bf16 bf16x8 __attribute__((ext_vector_type(8)));
typedef __bf16 bf16x4 __attribute__((ext_vector_type(4)));

#define DEV __device__ __forceinline__

DEV void glds16(const __bf16* g, __bf16* l) {
  __builtin_amdgcn_global_load_lds((__attribute__((address_space(1))) void*)(g),
                                   (__attribute__((address_space(3))) void*)(l),
                                   16, 0, 0);
}

DEV float sanit(float v) {  // NaN/inf absorbing clamp
  return fminf(fmaxf(v, -1e30f), 1e30f);
}

// ============================================================
// f32 -> bf16 elementwise convert (4 elems/thread)
// ============================================================
__global__ __launch_bounds__(256) void cvt_bf16(const float* __restrict__ src,
                                                __bf16* __restrict__ dst)
{
  const int idx = blockIdx.x * 256 + threadIdx.x;
  const f32x4 v = ((const f32x4*)src)[idx];
  bf16x4 o;
#pragma unroll
  for (int i = 0; i < 4; i++) o[i] = (__bf16)v[i];
  ((bf16x4*)dst)[idx] = o;
}

// ============================================================
// LDS-tiled transpose+convert: src f32 [K][N] -> dst bf16 [N][K]
// ============================================================
__global__ __launch_bounds__(256) void wtrans(const float* __restrict__ src,
                                              __bf16* __restrict__ dst,
                                              int K, int N)
{
  __shared__ float t[64][65];
  const int k0 = blockIdx.y * 64, n0 = blockIdx.x * 64;
  const int c = threadIdx.x & 63, r0 = threadIdx.x >> 6;
#pragma unroll
  for (int i = 0; i < 16; i++) {
    const int r = r0 * 16 + i;
    t[r][c] = src[(size_t)(k0 + r) * N + n0 + c];
  }
  __syncthreads();
#pragma unroll
  for (int i = 0; i < 16; i++) {
    const int r = r0 * 16 + i;
    dst[(size_t)(n0 + r) * K + k0 + c] = (__bf16)t[c][r];
  }
}

// ============================================================
// LDS-tiled V transpose (bf16): dst[bh][d][s]
// ============================================================
__global__ __launch_bounds__(256) void vtrans(const __bf16* __restrict__ src,
                                              int stride, int colMul, int colAdd,
                                              __bf16* __restrict__ dst)
{
  __shared__ __bf16 t[64][66];
  const int bh = blockIdx.y, b = bh >> 4, h = bh & 15;
  const int s0 = blockIdx.x * 64;
  const int c = threadIdx.x & 63, r0 = threadIdx.x >> 6;
  const __bf16* sp = src + (size_t)(b * SS) * stride + h * colMul + colAdd;
#pragma unroll
  for (int i = 0; i < 16; i++) {
    const int s = r0 * 16 + i;
    t[s][c] = sp[(size_t)(s0 + s) * stride + c];
  }
  __syncthreads();
  __bf16* dp = dst + (size_t)bh * 64 * 1024;
#pragma unroll
  for (int i = 0; i < 16; i++) {
    const int d = r0 * 16 + i;
    dp[(size_t)d * 1024 + s0 + c] = t[c][d];
  }
}

// ============================================================
// GEMM 128x128 (m97 structure) — for N>=2048 shapes (qkv, w1)
// MODE 0: bf16 out; 1: gelu->bf16; 2: f32 out;
// MODE 3: bf16 out, scale Q-cols of fused qkv ((col%192)<64) by SCL_L2E
// ============================================================
template<int MODE>
__global__ __launch_bounds__(256) void gemm_bt(
    const __bf16* __restrict__ A, const __bf16* __restrict__ Bt,
    const float* __restrict__ bias, void* __restrict__ Cout,
    int N, int K)
{
  __shared__ __align__(16) __bf16 As[128 * 32];
  __shared__ __align__(16) __bf16 Bs[128 * 32];

  const int bm = blockIdx.y * 128, bn = blockIdx.x * 128;
  const int tid = threadIdx.x, wid = tid >> 6, lane = tid & 63;
  const int quad = lane >> 4, ln = lane & 15;

  const __bf16* gA = A  + (size_t)(bm + wid * 32 + (lane >> 2)) * K + (lane & 3) * 8;
  const __bf16* gB = Bt + (size_t)(bn + wid * 32 + (lane >> 2)) * K + (lane & 3) * 8;
  __bf16* lA = As + (wid * 32) * 32;
  __bf16* lB = Bs + (wid * 32) * 32;

  f32x4 acc[4][4];
#pragma unroll
  for (int i = 0; i < 4; i++)
#pragma unroll
    for (int j = 0; j < 4; j++) acc[i][j] = (f32x4){0.f, 0.f, 0.f, 0.f};

  const int wr = (wid >> 1) * 64, wc = (wid & 1) * 64;

  for (int k0 = 0; k0 < K; k0 += 32) {
    glds16(gA + k0,           lA);
    glds16(gA + 16 * K + k0,  lA + 16 * 32);
    glds16(gB + k0,           lB);
    glds16(gB + 16 * K + k0,  lB + 16 * 32);
    __syncthreads();

    bf16x8 af[4], bfr[4];
#pragma unroll
    for (int i = 0; i < 4; i++)
      af[i] = *(const bf16x8*)(As + (wr + i * 16 + ln) * 32 + quad * 8);
#pragma unroll
    for (int j = 0; j < 4; j++)
      bfr[j] = *(const bf16x8*)(Bs + (wc + j * 16 + ln) * 32 + quad * 8);
#pragma unroll
    for (int i = 0; i < 4; i++)
#pragma unroll
      for (int j = 0; j < 4; j++)
        acc[i][j] = __builtin_amdgcn_mfma_f32_16x16x32_bf16(af[i], bfr[j], acc[i][j], 0, 0, 0);
    __syncthreads();
  }

#pragma unroll
  for (int j = 0; j < 4; j++) {
    const int col = bn + wc + j * 16 + ln;
    const float bv = bias[col];
#pragma unroll
    for (int i = 0; i < 4; i++) {
#pragma unroll
      for (int r = 0; r < 4; r++) {
        const int row = bm + wr + i * 16 + quad * 4 + r;
        float v = sanit(acc[i][j][r] + bv);
        if (MODE == 1) v = 0.5f * v * (1.f + erff(v * 0.70710678118654752f));
        if (MODE == 3 && (col % 192) < 64) v *= SCL_L2E;
        if (MODE == 2) ((float*)Cout)[(size_t)row * N + col] = v;
        else           ((__bf16*)Cout)[(size_t)row * N + col] = (__bf16)v;
      }
    }
  }
}

// ============================================================
// GEMM 128x64 — for N=1024 shapes (2 blocks/CU)
// MODE 0: bf16; 2: f32; 3: bf16 scaled by SCL_L2E (cross-attn Q)
// ============================================================
template<int MODE>
__global__ __launch_bounds__(256) void gemm_bt64(
    const __bf16* __restrict__ A, const __bf16* __restrict__ Bt,
    const float* __restrict__ bias, void* __restrict__ Cout,
    int N, int K)
{
  __shared__ __align__(16) __bf16 As[128 * 32];
  __shared__ __align__(16) __bf16 Bs[64 * 32];

  const int bm = blockIdx.y * 128, bn = blockIdx.x * 64;
  const int tid = threadIdx.x, wid = tid >> 6, lane = tid & 63;
  const int quad = lane >> 4, ln = lane & 15;

  const __bf16* gA = A  + (size_t)(bm + wid * 32 + (lane >> 2)) * K + (lane & 3) * 8;
  const __bf16* gB = Bt + (size_t)(bn + wid * 16 + (lane >> 2)) * K + (lane & 3) * 8;
  __bf16* lA = As + (wid * 32) * 32;
  __bf16* lB = Bs + (wid * 16) * 32;

  f32x4 acc[4][2];
#pragma unroll
  for (int i = 0; i < 4; i++)
#pragma unroll
    for (int j = 0; j < 2; j++) acc[i][j] = (f32x4){0.f, 0.f, 0.f, 0.f};

  const int wr = (wid >> 1) * 64, wc = (wid & 1) * 32;

  for (int k0 = 0; k0 < K; k0 += 32) {
    glds16(gA + k0,           lA);
    glds16(gA + 16 * K + k0,  lA + 16 * 32);
    glds16(gB + k0,           lB);
    __syncthreads();

    bf16x8 af[4], bfr[2];
#pragma unroll
    for (int i = 0; i < 4; i++)
      af[i] = *(const bf16x8*)(As + (wr + i * 16 + ln) * 32 + quad * 8);
#pragma unroll
    for (int j = 0; j < 2; j++)
      bfr[j] = *(const bf16x8*)(Bs + (wc + j * 16 + ln) * 32 + quad * 8);
#pragma unroll
    for (int i = 0; i < 4; i++)
#pragma unroll
      for (int j = 0; j < 2; j++)
        acc[i][j] = __builtin_amdgcn_mfma_f32_16x16x32_bf16(af[i], bfr[j], acc[i][j], 0, 0, 0);
    __syncthreads();
  }

#pragma unroll
  for (int j = 0; j < 2; j++) {
    const int col = bn + wc + j * 16 + ln;
    const float bv = bias[col];
#pragma unroll
    for (int i = 0; i < 4; i++) {
#pragma unroll
      for (int r = 0; r < 4; r++) {
        const int row = bm + wr + i * 16 + quad * 4 + r;
        float v = sanit(acc[i][j][r] + bv);
        if (MODE == 3) v *= SCL_L2E;
        if (MODE == 2) ((float*)Cout)[(size_t)row * N + col] = v;
        else           ((__bf16*)Cout)[(size_t)row * N + col] = (__bf16)v;
      }
    }
  }
}

// ============================================================
// Flash attention R9: block = 128 Q rows (4 waves x 32 rows),
// K/V tiles staged ONCE per block into LDS via global_load_lds
// (double-buffered, counted vmcnt(4), raw s_barrier), XOR-swizzled
// LDS layouts (K, V^T, P) so every ds_read_b128 is at the 8-cycle
// bank floor. Q is pre-scaled by 0.125*log2(e) in the projection
// GEMMs, so softmax is a bare exp2f. Fixed-shift softmax (no max
// tracking), per-wave P tile -> no cross-wave merge.
// grid = 512 (8 bh_hi x 8 qblk x 8 bh_lo for XCD locality); block 256.
// LDS: K 2x8KB + V 2x8KB + P 4x4KB = 48 KB.
// ============================================================
__global__ __launch_bounds__(256) void attn(
    const __bf16* __restrict__ qp, int qStride, int qMul, int qAdd,
    const __bf16* __restrict__ kp, int kStride, int kMul, int kAdd,
    const __bf16* __restrict__ vt, __bf16* __restrict__ outp, int causal)
{
  __shared__ __align__(16) __bf16 Kt[2][64 * 64];   // [buf][row][64] swizzled
  __shared__ __align__(16) __bf16 Vt[2][64 * 64];   // [buf][dh][64]  swizzled
  __shared__ __align__(16) __bf16 ptl[4][32 * 64];  // per-wave P, swizzled

  const int id = blockIdx.x;
  const int bh = ((id >> 6) << 3) | (id & 7);       // keep bh%8 == id%8 (XCD)
  const int qblk = (id >> 3) & 7;
  const int b = bh >> 4, h = bh & 15;
  const int tid = threadIdx.x, wid = tid >> 6, lane = tid & 63;
  const int quad = lane >> 4, ln = lane & 15;
  const int qbase = qblk * 128;
  const int rowb0 = qbase + wid * 32;               // wave's first Q row
  const int rowTop = rowb0 + 31;

  // ---- Q fragments in registers: A[m=ln][k=quad*8+j] ----
  bf16x8 aq[2][2];
#pragma unroll
  for (int rf = 0; rf < 2; ++rf) {
    const __bf16* qr = qp + (size_t)(b * SS + rowb0 + rf * 16 + ln) * qStride
                          + h * qMul + qAdd;
#pragma unroll
    for (int ks = 0; ks < 2; ++ks)
      aq[rf][ks] = *(const bf16x8*)(qr + ks * 32 + quad * 8);
  }

  f32x4 acc[2][4];
#pragma unroll
  for (int rf = 0; rf < 2; ++rf)
#pragma unroll
    for (int nb = 0; nb < 4; ++nb) acc[rf][nb] = (f32x4){0.f, 0.f, 0.f, 0.f};
  float l_r[2][4] = {{0.f,0.f,0.f,0.f},{0.f,0.f,0.f,0.f}};

  const __bf16* kbase = kp + (size_t)(b * SS) * kStride + h * kMul + kAdd;
  const __bf16* vtb = vt + (size_t)bh * 64 * 1024;
  __bf16* ptw = ptl[wid];

  const int kvEnd = causal ? (qbase + 128) : SS;
  const int nT = kvEnd >> 6;

  // staging geometry: lane covers linear LDS row r = wave_quarter + lane/8,
  // 16B granule q = lane%8. Global source pre-swizzled: granule q holds
  // global granule q^(r&7)  (rule #21: linear dest + inv-swz source).
  const int sr = wid * 16 + (lane >> 3);   // +8 for p=1
  const int sq = lane & 7;

  // prologue: stage tile 0
#pragma unroll
  for (int p = 0; p < 2; ++p) {
    const int r = sr + p * 8;
    const int qs = (sq ^ (r & 7)) * 8;
    glds16(kbase + (size_t)r * kStride + qs, Kt[0] + (wid * 2 + p) * 512);
    glds16(vtb + (size_t)r * 1024 + qs,      Vt[0] + (wid * 2 + p) * 512);
  }

  for (int t = 0; t < nT; ++t) {
    const int cur = t & 1;
    const int kv0 = t * 64;

    if (t + 1 < nT) {
      const int kn = kv0 + 64;
#pragma unroll
      for (int p = 0; p < 2; ++p) {
        const int r = sr + p * 8;
        const int qs = (sq ^ (r & 7)) * 8;
        glds16(kbase + (size_t)(kn + r) * kStride + qs, Kt[cur ^ 1] + (wid * 2 + p) * 512);
        glds16(vtb + (size_t)r * 1024 + kn + qs,        Vt[cur ^ 1] + (wid * 2 + p) * 512);
      }
      __asm__ volatile("s_waitcnt vmcnt(4)" ::: "memory");  // tile t landed (mine)
    } else {
      __asm__ volatile("s_waitcnt vmcnt(0)" ::: "memory");
    }
    __builtin_amdgcn_sched_barrier(0);
    __builtin_amdgcn_s_barrier();              // everyone's quarter landed
    __asm__ volatile("" ::: "memory");
    __builtin_amdgcn_sched_barrier(0);

    if (!causal || kv0 <= rowTop) {
      const __bf16* kt = Kt[cur];
      const __bf16* vv = Vt[cur];

      // ---- QK^T: 16 MFMA, swizzled K reads (8-cycle bank floor) ----
      f32x4 sc[2][4];
      {
        bf16x8 kf[4][2];
#pragma unroll
        for (int c = 0; c < 4; ++c) {
          const int row = c * 16 + ln;
#pragma unroll
          for (int ks = 0; ks < 2; ++ks)
            kf[c][ks] = *(const bf16x8*)(kt + row * 64 + (((ks * 4 + quad) ^ (ln & 7)) * 8));
        }
#pragma unroll
        for (int rf = 0; rf < 2; ++rf)
#pragma unroll
          for (int c = 0; c < 4; ++c) {
            f32x4 s_ = (f32x4){0.f, 0.f, 0.f, 0.f};
            s_ = __builtin_amdgcn_mfma_f32_16x16x32_bf16(aq[rf][0], kf[c][0], s_, 0, 0, 0);
            s_ = __builtin_amdgcn_mfma_f32_16x16x32_bf16(aq[rf][1], kf[c][1], s_, 0, 0, 0);
            sc[rf][c] = s_;
          }
      }

      // ---- softmax (Q pre-scaled -> bare exp2) + swizzled P write ----
#pragma unroll
      for (int rf = 0; rf < 2; ++rf) {
        const bool doMask = causal && (kv0 + 63 > rowb0 + rf * 16);
#pragma unroll
        for (int r = 0; r < 4; ++r) {
          const int rowg = rowb0 + rf * 16 + quad * 4 + r;
          float p[4];
#pragma unroll
          for (int c = 0; c < 4; ++c) {
            float e = sc[rf][c][r];
            if (doMask && (kv0 + c * 16 + ln > rowg)) e = NEG_BIG;
            p[c] = exp2f(e);
          }
          l_r[rf][r] += (p[0] + p[1]) + (p[2] + p[3]);
          const int m = rf * 16 + quad * 4 + r;
          __bf16* pr = ptw + m * 64;
#pragma unroll
          for (int c = 0; c < 4; ++c) {
            const int col = c * 16 + ln;
            pr[(((col >> 3) ^ (m & 7)) << 3) + (col & 7)] = (__bf16)p[c];
          }
        }
      }
      __asm__ volatile("s_waitcnt lgkmcnt(0)" ::: "memory");
      __builtin_amdgcn_sched_barrier(0);

      // ---- PV: 16 MFMA, swizzled P / V reads ----
      {
        bf16x8 pa[2][2];
#pragma unroll
        for (int rf = 0; rf < 2; ++rf) {
          const int m = rf * 16 + ln;
#pragma unroll
          for (int ks = 0; ks < 2; ++ks)
            pa[rf][ks] = *(const bf16x8*)(ptw + m * 64 + (((ks * 4 + quad) ^ (m & 7)) * 8));
        }
#pragma unroll
        for (int nb = 0; nb < 4; ++nb) {
          const int vrow = nb * 16 + ln;
          const bf16x8 vf0 = *(const bf16x8*)(vv + vrow * 64 + (((quad)     ^ (ln & 7)) * 8));
          const bf16x8 vf1 = *(const bf16x8*)(vv + vrow * 64 + (((4 + quad) ^ (ln & 7)) * 8));
#pragma unroll
          for (int rf = 0; rf < 2; ++rf) {
            acc[rf][nb] = __builtin_amdgcn_mfma_f32_16x16x32_bf16(pa[rf][0], vf0, acc[rf][nb], 0, 0, 0);
            acc[rf][nb] = __builtin_amdgcn_mfma_f32_16x16x32_bf16(pa[rf][1], vf1, acc[rf][nb], 0, 0, 0);
          }
        }
      }
    }

    __asm__ volatile("" ::: "memory");
    __builtin_amdgcn_sched_barrier(0);
    __builtin_amdgcn_s_barrier();              // buf[cur] free for next stage
  }

  // ---- finalize: row-sum over the 16 lanes of each ln group ----
#pragma unroll
  for (int rf = 0; rf < 2; ++rf) {
#pragma unroll
    for (int r = 0; r < 4; ++r) {
      float l = l_r[rf][r];
#pragma unroll
      for (int off = 1; off < 16; off <<= 1) l += __shfl_xor(l, off, 64);
      const float inv = 1.f / fmaxf(l, 1e-30f);
      const int rowg = rowb0 + rf * 16 + quad * 4 + r;
      __bf16* op = outp + (size_t)(b * SS + rowg) * DD + h * 64;
#pragma unroll
      for (int nb = 0; nb < 4; ++nb)
        op[nb * 16 + ln] = (__bf16)sanit(acc[rf][nb][r] * inv);
    }
  }
}

// ============================================================
// LayerNorm rows of 1024 (unchanged)
// ============================================================
__global__ __launch_bounds__(256) void ln_k(
    const float* __restrict__ residf, const float* __restrict__ proj,
    const float* __restrict__ g, const float* __restrict__ be,
    float* __restrict__ outf, __bf16* __restrict__ outb)
{
  const int row = blockIdx.x, tid = threadIdx.x;
  const f32x4 pb = ((const f32x4*)(proj   + (size_t)row * 1024))[tid];
  const f32x4 rb = ((const f32x4*)(residf + (size_t)row * 1024))[tid];
  f32x4 x;
#pragma unroll
  for (int i = 0; i < 4; i++)
    x[i] = fminf(fmaxf(pb[i] + rb[i], -1e15f), 1e15f);
  float s  = x[0] + x[1] + x[2] + x[3];
  float ss = x[0]*x[0] + x[1]*x[1] + x[2]*x[2] + x[3]*x[3];
#pragma unroll
  for (int off = 1; off < 64; off <<= 1) {
    s  += __shfl_xor(s,  off, 64);
    ss += __shfl_xor(ss, off, 64);
  }
  __shared__ float sm[8];
  if ((tid & 63) == 0) { sm[tid >> 6] = s; sm[4 + (tid >> 6)] = ss; }
  __syncthreads();
  s  = sm[0] + sm[1] + sm[2] + sm[3];
  ss = sm[4] + sm[5] + sm[6] + sm[7];
  const float mean = s * (1.f / 1024.f);
  const float var  = fmaxf(ss * (1.f / 1024.f) - mean * mean, 0.f);
  const float rstd = rsqrtf(var + 1e-5f);
  const int c = tid * 4;
  f32x4 o;
#pragma unroll
  for (int i = 0; i < 4; i++)
    o[i] = g[c + i] * ((x[i] - mean) * rstd) + be[c + i];
  if (outf) ((f32x4*)(outf + (size_t)row * 1024))[tid] = o;
  if (outb) {
    bf16x4 ob;
#pragma unroll
    for (int i = 0; i < 4; i++) ob[i] = (__bf16)o[i];
    ((bf16x4*)(outb + (size_t)row * 1024))[tid] = ob;
  }
}

// ============================================================
extern "C" void kernel_launch(void* const* d_in, const int* in_sizes, int n_in,
                              void* d_out, int out_size, void* d_ws, size_t ws_size,
                              hipStream_t stream)
{
  const float* x      = (const float*)d_in[0];
  const float* enc    = (const float*)d_in[1];
  const float* w_qkv  = (const float*)d_in[2];
  const float* b_qkv  = (const float*)d_in[3];
  const float* w_sa_o = (const float*)d_in[4];
  const float* b_sa_o = (const float*)d_in[5];
  const float* w_q    = (const float*)d_in[6];
  const float* b_q    = (const float*)d_in[7];
  const float* w_k    = (const float*)d_in[8];
  const float* b_k    = (const float*)d_in[9];
  const float* w_v    = (const float*)d_in[10];
  const float* b_v    = (const float*)d_in[11];
  const float* w_ca_o = (const float*)d_in[12];
  const float* b_ca_o = (const float*)d_in[13];
  const float* w1     = (const float*)d_in[14];
  const float* b1     = (const float*)d_in[15];
  const float* w2     = (const float*)d_in[16];
  const float* b2     = (const float*)d_in[17];
  const float* g1     = (const float*)d_in[18];
  const float* be1    = (const float*)d_in[19];
  const float* g2     = (const float*)d_in[20];
  const float* be2    = (const float*)d_in[21];
  const float* g3     = (const float*)d_in[22];
  const float* be3    = (const float*)d_in[23];

  // ---- workspace layout, peak ~136 MB ----
  const size_t MB = 1024 * 1024;
  char* base = (char*)d_ws;
  __bf16* wqkvT = (__bf16*)(base + 0 * MB);
  __bf16* wsaoT = (__bf16*)(base + 6 * MB);
  __bf16* wqT   = (__bf16*)(base + 8 * MB);
  __bf16* wkT   = (__bf16*)(base + 10 * MB);
  __bf16* wvT   = (__bf16*)(base + 12 * MB);
  __bf16* wcaoT = (__bf16*)(base + 14 * MB);
  __bf16* w1T   = (__bf16*)(base + 0 * MB);    // overlays small weights, post-CA
  __bf16* w2T   = (__bf16*)(base + 8 * MB);
  __bf16* xb    = (__bf16*)(base + 16 * MB);
  __bf16* encb  = (__bf16*)(base + 24 * MB);
  __bf16* qkv   = (__bf16*)(base + 32 * MB);   // 24 MB
  __bf16* vt    = (__bf16*)(base + 56 * MB);   // 8 MB
  __bf16* mid   = (__bf16*)(base + 32 * MB);   // overlays qkv+vt in FFN phase
  __bf16* attnb = (__bf16*)(base + 64 * MB);
  float*  proj  = (float*) (base + 72 * MB);
  float*  h1f   = (float*) (base + 88 * MB);
  __bf16* h1b   = (__bf16*)(base + 104 * MB);
  float*  h2f   = (float*) (base + 112 * MB);
  __bf16* h2b   = (__bf16*)(base + 128 * MB);
  __bf16* qb = qkv;
  __bf16* kb = qkv + (size_t)MROWS * 1024;
  __bf16* vb = qkv + (size_t)MROWS * 2048;

  // ---- input converts + early weight transposes ----
  cvt_bf16<<<4096, 256, 0, stream>>>(x,   xb);
  cvt_bf16<<<4096, 256, 0, stream>>>(enc, encb);
  wtrans<<<dim3(48, 16), 256, 0, stream>>>(w_qkv,  wqkvT, 1024, 3072);
  wtrans<<<dim3(16, 16), 256, 0, stream>>>(w_sa_o, wsaoT, 1024, 1024);
  wtrans<<<dim3(16, 16), 256, 0, stream>>>(w_q,    wqT,   1024, 1024);
  wtrans<<<dim3(16, 16), 256, 0, stream>>>(w_k,    wkT,   1024, 1024);
  wtrans<<<dim3(16, 16), 256, 0, stream>>>(w_v,    wvT,   1024, 1024);
  wtrans<<<dim3(16, 16), 256, 0, stream>>>(w_ca_o, wcaoT, 1024, 1024);

  // ---- self-attention (Q pre-scaled by 0.125*log2e in MODE 3) ----
  gemm_bt<3><<<dim3(24, 32), 256, 0, stream>>>(xb, wqkvT, b_qkv, qkv, 3072, 1024);
  vtrans<<<dim3(16, 64), 256, 0, stream>>>(qkv, 3072, 192, 128, vt);
  attn<<<512, 256, 0, stream>>>(qkv, 3072, 192, 0,
                                qkv, 3072, 192, 64, vt, attnb, 1);
  gemm_bt64<2><<<dim3(16, 32), 256, 0, stream>>>(attnb, wsaoT, b_sa_o, proj, 1024, 1024);
  ln_k<<<4096, 256, 0, stream>>>(x, proj, g1, be1, h1f, h1b);

  // ---- cross-attention ----
  gemm_bt64<3><<<dim3(16, 32), 256, 0, stream>>>(h1b, wqT, b_q, qb, 1024, 1024);
  gemm_bt64<0><<<dim3(16, 32), 256, 0, stream>>>(encb, wkT, b_k, kb, 1024, 1024);
  gemm_bt64<0><<<dim3(16, 32), 256, 0, stream>>>(encb, wvT, b_v, vb, 1024, 1024);
  vtrans<<<dim3(16, 64), 256, 0, stream>>>(vb, 1024, 64, 0, vt);
  attn<<<512, 256, 0, stream>>>(qb, 1024, 64, 0,
                                kb, 1024, 64, 0, vt, attnb, 0);
  gemm_bt64<2><<<dim3(16, 32), 256, 0, stream>>>(attnb, wcaoT, b_ca_o, proj, 1024, 1024);
  ln_k<<<4096, 256, 0, stream>>>(h1f, proj, g2, be2, h2f, h2b);

  // ---- FFN ----
  wtrans<<<dim3(64, 16), 256, 0, stream>>>(w1, w1T, 1024, 4096);
  wtrans<<<dim3(16, 64), 256, 0, stream>>>(w2, w2T, 4096, 1024);
  gemm_bt<1><<<dim3(32, 32), 256, 0, stream>>>(h2b, w1T, b1, mid, 4096, 1024);
  gemm_bt64<2><<<dim3(16, 32), 256, 0, stream>>>(mid, w2T, b2, proj, 1024, 4096);
  ln_k<<<4096, 256, 0, stream>>>(h2f, proj, g3, be3, (float*)d_out, nullptr);

  (void)in_sizes; (void)n_in; (void)out_size; (void)ws_size;
}

// Round 3
// 597.690 us; speedup vs baseline: 1.1847x; 1.0150x over previous
//
#include <hip/hip_runtime.h>

// ---- problem constants ----
#define BB 4
#define SS 1024
#define DD 1024
#define HH 16
#define DHH 64
#define DFF 4096
#define MROWS 4096   // B*S
#define NEG_BIG (-1e30f)
#define LOG2E 1.4426950408889634f
#define SCL_L2E 0.1803368801111244f   // 0.125 * log2(e)

typedef float  f32x4  __attribute__((ext_vector_type(4)));
typedef __bf16 bf16x8 __attribute__((ext_vector_type(8)));
typedef __bf16 bf16x4 __attribute__((ext_vector_type(4)));

#define DEV __device__ __forceinline__

DEV void glds16(const __bf16* g, __bf16* l) {
  __builtin_amdgcn_global_load_lds((__attribute__((address_space(1))) void*)(g),
                                   (__attribute__((address_space(3))) void*)(l),
                                   16, 0, 0);
}

DEV float sanit(float v) {  // NaN/inf absorbing clamp
  return fminf(fmaxf(v, -1e30f), 1e30f);
}

// exact-GELU via A&S 7.1.26 erf (|err|<=1.5e-7, invisible at bf16).
// Replaces ocml erff (heavier VALU sequence) in the FFN1 epilogue.
DEV float gelu_f(float v) {
  const float z  = fabsf(v) * 0.70710678118654752f;
  const float t  = __builtin_amdgcn_rcpf(1.f + 0.3275911f * z);
  float poly = ((((1.061405429f * t - 1.453152027f) * t + 1.421413741f) * t
                 - 0.284496736f) * t + 0.254829592f) * t;
  float er = 1.f - poly * __expf(-z * z);
  er = copysignf(er, v);
  return 0.5f * v * (1.f + er);
}

// ============================================================
// f32 -> bf16 elementwise convert (4 elems/thread)
// ============================================================
__global__ __launch_bounds__(256) void cvt_bf16(const float* __restrict__ src,
                                                __bf16* __restrict__ dst)
{
  const int idx = blockIdx.x * 256 + threadIdx.x;
  const f32x4 v = ((const f32x4*)src)[idx];
  bf16x4 o;
#pragma unroll
  for (int i = 0; i < 4; i++) o[i] = (__bf16)v[i];
  ((bf16x4*)dst)[idx] = o;
}

// ============================================================
// LDS-tiled transpose+convert: src f32 [K][N] -> dst bf16 [N][K]
// ============================================================
__global__ __launch_bounds__(256) void wtrans(const float* __restrict__ src,
                                              __bf16* __restrict__ dst,
                                              int K, int N)
{
  __shared__ float t[64][65];
  const int k0 = blockIdx.y * 64, n0 = blockIdx.x * 64;
  const int c = threadIdx.x & 63, r0 = threadIdx.x >> 6;
#pragma unroll
  for (int i = 0; i < 16; i++) {
    const int r = r0 * 16 + i;
    t[r][c] = src[(size_t)(k0 + r) * N + n0 + c];
  }
  __syncthreads();
#pragma unroll
  for (int i = 0; i < 16; i++) {
    const int r = r0 * 16 + i;
    dst[(size_t)(n0 + r) * K + k0 + c] = (__bf16)t[c][r];
  }
}

// ============================================================
// LDS-tiled V transpose (bf16): dst[bh][d][s]
// ============================================================
__global__ __launch_bounds__(256) void vtrans(const __bf16* __restrict__ src,
                                              int stride, int colMul, int colAdd,
                                              __bf16* __restrict__ dst)
{
  __shared__ __bf16 t[64][66];
  const int bh = blockIdx.y, b = bh >> 4, h = bh & 15;
  const int s0 = blockIdx.x * 64;
  const int c = threadIdx.x & 63, r0 = threadIdx.x >> 6;
  const __bf16* sp = src + (size_t)(b * SS) * stride + h * colMul + colAdd;
#pragma unroll
  for (int i = 0; i < 16; i++) {
    const int s = r0 * 16 + i;
    t[s][c] = sp[(size_t)(s0 + s) * stride + c];
  }
  __syncthreads();
  __bf16* dp = dst + (size_t)bh * 64 * 1024;
#pragma unroll
  for (int i = 0; i < 16; i++) {
    const int d = r0 * 16 + i;
    dp[(size_t)d * 1024 + s0 + c] = t[c][d];
  }
}

// ============================================================
// GEMM 128x128, 2-phase double-buffered (T3 minimum recipe):
// issue next tile's global_load_lds BEFORE computing current tile;
// one __syncthreads (vmcnt(0)+barrier) per K-step. Load latency
// hides under ds_read+MFMA of the current tile.
// MODE 0: bf16 out; 1: gelu->bf16; 2: f32 out;
// MODE 3: bf16 out, scale Q-cols of fused qkv ((col%192)<64) by SCL_L2E
// ============================================================
template<int MODE>
__global__ __launch_bounds__(256) void gemm_bt(
    const __bf16* __restrict__ A, const __bf16* __restrict__ Bt,
    const float* __restrict__ bias, void* __restrict__ Cout,
    int N, int K)
{
  __shared__ __align__(16) __bf16 As[2][128 * 32];
  __shared__ __align__(16) __bf16 Bs[2][128 * 32];

  const int bm = blockIdx.y * 128, bn = blockIdx.x * 128;
  const int tid = threadIdx.x, wid = tid >> 6, lane = tid & 63;
  const int quad = lane >> 4, ln = lane & 15;

  const __bf16* gA = A  + (size_t)(bm + wid * 32 + (lane >> 2)) * K + (lane & 3) * 8;
  const __bf16* gB = Bt + (size_t)(bn + wid * 32 + (lane >> 2)) * K + (lane & 3) * 8;
  const int soff = (wid * 32) * 32;

  f32x4 acc[4][4];
#pragma unroll
  for (int i = 0; i < 4; i++)
#pragma unroll
    for (int j = 0; j < 4; j++) acc[i][j] = (f32x4){0.f, 0.f, 0.f, 0.f};

  const int wr = (wid >> 1) * 64, wc = (wid & 1) * 64;

#define G_STAGE(buf, kt) do {                                     \
    const int k0_ = (kt) * 32;                                    \
    glds16(gA + k0_,          &As[buf][soff]);                    \
    glds16(gA + 16 * K + k0_, &As[buf][soff + 16 * 32]);          \
    glds16(gB + k0_,          &Bs[buf][soff]);                    \
    glds16(gB + 16 * K + k0_, &Bs[buf][soff + 16 * 32]);          \
  } while (0)

#define G_COMP(buf) do {                                                    \
    bf16x8 af[4], bfr[4];                                                   \
    _Pragma("unroll")                                                       \
    for (int i = 0; i < 4; i++)                                             \
      af[i] = *(const bf16x8*)(&As[buf][(wr + i * 16 + ln) * 32 + quad * 8]); \
    _Pragma("unroll")                                                       \
    for (int j = 0; j < 4; j++)                                             \
      bfr[j] = *(const bf16x8*)(&Bs[buf][(wc + j * 16 + ln) * 32 + quad * 8]); \
    _Pragma("unroll")                                                       \
    for (int i = 0; i < 4; i++)                                             \
      _Pragma("unroll")                                                     \
      for (int j = 0; j < 4; j++)                                           \
        acc[i][j] = __builtin_amdgcn_mfma_f32_16x16x32_bf16(af[i], bfr[j], acc[i][j], 0, 0, 0); \
  } while (0)

  const int nk = K >> 5;              // K-steps of 32; K%64==0 -> nk even
  G_STAGE(0, 0);
  __syncthreads();
  for (int kt = 0; kt < nk; kt += 2) {
    G_STAGE(1, kt + 1);               // prefetch next tile
    G_COMP(0);
    __syncthreads();                  // vmcnt(0)+barrier: tile kt+1 landed
    if (kt + 2 < nk) G_STAGE(0, kt + 2);
    G_COMP(1);
    __syncthreads();
  }
#undef G_STAGE
#undef G_COMP

#pragma unroll
  for (int j = 0; j < 4; j++) {
    const int col = bn + wc + j * 16 + ln;
    const float bv = bias[col];
#pragma unroll
    for (int i = 0; i < 4; i++) {
#pragma unroll
      for (int r = 0; r < 4; r++) {
        const int row = bm + wr + i * 16 + quad * 4 + r;
        float v = sanit(acc[i][j][r] + bv);
        if (MODE == 1) v = gelu_f(v);
        if (MODE == 3 && (col % 192) < 64) v *= SCL_L2E;
        if (MODE == 2) ((float*)Cout)[(size_t)row * N + col] = v;
        else           ((__bf16*)Cout)[(size_t)row * N + col] = (__bf16)v;
      }
    }
  }
}

// ============================================================
// GEMM 128x64, 2-phase double-buffered — for N=1024 shapes
// MODE 0: bf16; 2: f32; 3: bf16 scaled by SCL_L2E (cross-attn Q)
// ============================================================
template<int MODE>
__global__ __launch_bounds__(256) void gemm_bt64(
    const __bf16* __restrict__ A, const __bf16* __restrict__ Bt,
    const float* __restrict__ bias, void* __restrict__ Cout,
    int N, int K)
{
  __shared__ __align__(16) __bf16 As[2][128 * 32];
  __shared__ __align__(16) __bf16 Bs[2][64 * 32];

  const int bm = blockIdx.y * 128, bn = blockIdx.x * 64;
  const int tid = threadIdx.x, wid = tid >> 6, lane = tid & 63;
  const int quad = lane >> 4, ln = lane & 15;

  const __bf16* gA = A  + (size_t)(bm + wid * 32 + (lane >> 2)) * K + (lane & 3) * 8;
  const __bf16* gB = Bt + (size_t)(bn + wid * 16 + (lane >> 2)) * K + (lane & 3) * 8;
  const int aoff = (wid * 32) * 32;
  const int boff = (wid * 16) * 32;

  f32x4 acc[4][2];
#pragma unroll
  for (int i = 0; i < 4; i++)
#pragma unroll
    for (int j = 0; j < 2; j++) acc[i][j] = (f32x4){0.f, 0.f, 0.f, 0.f};

  const int wr = (wid >> 1) * 64, wc = (wid & 1) * 32;

#define G_STAGE(buf, kt) do {                                     \
    const int k0_ = (kt) * 32;                                    \
    glds16(gA + k0_,          &As[buf][aoff]);                    \
    glds16(gA + 16 * K + k0_, &As[buf][aoff + 16 * 32]);          \
    glds16(gB + k0_,          &Bs[buf][boff]);                    \
  } while (0)

#define G_COMP(buf) do {                                                    \
    bf16x8 af[4], bfr[2];                                                   \
    _Pragma("unroll")                                                       \
    for (int i = 0; i < 4; i++)                                             \
      af[i] = *(const bf16x8*)(&As[buf][(wr + i * 16 + ln) * 32 + quad * 8]); \
    _Pragma("unroll")                                                       \
    for (int j = 0; j < 2; j++)                                             \
      bfr[j] = *(const bf16x8*)(&Bs[buf][(wc + j * 16 + ln) * 32 + quad * 8]); \
    _Pragma("unroll")                                                       \
    for (int i = 0; i < 4; i++)                                             \
      _Pragma("unroll")                                                     \
      for (int j = 0; j < 2; j++)                                           \
        acc[i][j] = __builtin_amdgcn_mfma_f32_16x16x32_bf16(af[i], bfr[j], acc[i][j], 0, 0, 0); \
  } while (0)

  const int nk = K >> 5;
  G_STAGE(0, 0);
  __syncthreads();
  for (int kt = 0; kt < nk; kt += 2) {
    G_STAGE(1, kt + 1);
    G_COMP(0);
    __syncthreads();
    if (kt + 2 < nk) G_STAGE(0, kt + 2);
    G_COMP(1);
    __syncthreads();
  }
#undef G_STAGE
#undef G_COMP

#pragma unroll
  for (int j = 0; j < 2; j++) {
    const int col = bn + wc + j * 16 + ln;
    const float bv = bias[col];
#pragma unroll
    for (int i = 0; i < 4; i++) {
#pragma unroll
      for (int r = 0; r < 4; r++) {
        const int row = bm + wr + i * 16 + quad * 4 + r;
        float v = sanit(acc[i][j][r] + bv);
        if (MODE == 3) v *= SCL_L2E;
        if (MODE == 2) ((float*)Cout)[(size_t)row * N + col] = v;
        else           ((__bf16*)Cout)[(size_t)row * N + col] = (__bf16)v;
      }
    }
  }
}

// ============================================================
// Flash attention R9 (unchanged from round 2's passing version):
// block = 128 Q rows (4 waves x 32 rows), K/V staged once per block
// via global_load_lds (double-buffered, counted vmcnt(4), raw
// s_barrier), XOR-swizzled LDS (K, V^T, P). Q pre-scaled by
// 0.125*log2e in the projection GEMMs -> softmax is bare exp2f.
// grid = 512; block 256. LDS 48 KB.
// ============================================================
__global__ __launch_bounds__(256) void attn(
    const __bf16* __restrict__ qp, int qStride, int qMul, int qAdd,
    const __bf16* __restrict__ kp, int kStride, int kMul, int kAdd,
    const __bf16* __restrict__ vt, __bf16* __restrict__ outp, int causal)
{
  __shared__ __align__(16) __bf16 Kt[2][64 * 64];   // [buf][row][64] swizzled
  __shared__ __align__(16) __bf16 Vt[2][64 * 64];   // [buf][dh][64]  swizzled
  __shared__ __align__(16) __bf16 ptl[4][32 * 64];  // per-wave P, swizzled

  const int id = blockIdx.x;
  const int bh = ((id >> 6) << 3) | (id & 7);       // keep bh%8 == id%8 (XCD)
  const int qblk = (id >> 3) & 7;
  const int b = bh >> 4, h = bh & 15;
  const int tid = threadIdx.x, wid = tid >> 6, lane = tid & 63;
  const int quad = lane >> 4, ln = lane & 15;
  const int qbase = qblk * 128;
  const int rowb0 = qbase + wid * 32;               // wave's first Q row
  const int rowTop = rowb0 + 31;

  // ---- Q fragments in registers: A[m=ln][k=quad*8+j] ----
  bf16x8 aq[2][2];
#pragma unroll
  for (int rf = 0; rf < 2; ++rf) {
    const __bf16* qr = qp + (size_t)(b * SS + rowb0 + rf * 16 + ln) * qStride
                          + h * qMul + qAdd;
#pragma unroll
    for (int ks = 0; ks < 2; ++ks)
      aq[rf][ks] = *(const bf16x8*)(qr + ks * 32 + quad * 8);
  }

  f32x4 acc[2][4];
#pragma unroll
  for (int rf = 0; rf < 2; ++rf)
#pragma unroll
    for (int nb = 0; nb < 4; ++nb) acc[rf][nb] = (f32x4){0.f, 0.f, 0.f, 0.f};
  float l_r[2][4] = {{0.f,0.f,0.f,0.f},{0.f,0.f,0.f,0.f}};

  const __bf16* kbase = kp + (size_t)(b * SS) * kStride + h * kMul + kAdd;
  const __bf16* vtb = vt + (size_t)bh * 64 * 1024;
  __bf16* ptw = ptl[wid];

  const int kvEnd = causal ? (qbase + 128) : SS;
  const int nT = kvEnd >> 6;

  // staging geometry: lane covers linear LDS row r = wave_quarter + lane/8,
  // 16B granule q = lane%8. Global source pre-swizzled: granule q holds
  // global granule q^(r&7)  (rule #21: linear dest + inv-swz source).
  const int sr = wid * 16 + (lane >> 3);   // +8 for p=1
  const int sq = lane & 7;

  // prologue: stage tile 0
#pragma unroll
  for (int p = 0; p < 2; ++p) {
    const int r = sr + p * 8;
    const int qs = (sq ^ (r & 7)) * 8;
    glds16(kbase + (size_t)r * kStride + qs, Kt[0] + (wid * 2 + p) * 512);
    glds16(vtb + (size_t)r * 1024 + qs,      Vt[0] + (wid * 2 + p) * 512);
  }

  for (int t = 0; t < nT; ++t) {
    const int cur = t & 1;
    const int kv0 = t * 64;

    if (t + 1 < nT) {
      const int kn = kv0 + 64;
#pragma unroll
      for (int p = 0; p < 2; ++p) {
        const int r = sr + p * 8;
        const int qs = (sq ^ (r & 7)) * 8;
        glds16(kbase + (size_t)(kn + r) * kStride + qs, Kt[cur ^ 1] + (wid * 2 + p) * 512);
        glds16(vtb + (size_t)r * 1024 + kn + qs,        Vt[cur ^ 1] + (wid * 2 + p) * 512);
      }
      __asm__ volatile("s_waitcnt vmcnt(4)" ::: "memory");  // tile t landed (mine)
    } else {
      __asm__ volatile("s_waitcnt vmcnt(0)" ::: "memory");
    }
    __builtin_amdgcn_sched_barrier(0);
    __builtin_amdgcn_s_barrier();              // everyone's quarter landed
    __asm__ volatile("" ::: "memory");
    __builtin_amdgcn_sched_barrier(0);

    if (!causal || kv0 <= rowTop) {
      const __bf16* kt = Kt[cur];
      const __bf16* vv = Vt[cur];

      // ---- QK^T: 16 MFMA, swizzled K reads (8-cycle bank floor) ----
      f32x4 sc[2][4];
      {
        bf16x8 kf[4][2];
#pragma unroll
        for (int c = 0; c < 4; ++c) {
          const int row = c * 16 + ln;
#pragma unroll
          for (int ks = 0; ks < 2; ++ks)
            kf[c][ks] = *(const bf16x8*)(kt + row * 64 + (((ks * 4 + quad) ^ (ln & 7)) * 8));
        }
#pragma unroll
        for (int rf = 0; rf < 2; ++rf)
#pragma unroll
          for (int c = 0; c < 4; ++c) {
            f32x4 s_ = (f32x4){0.f, 0.f, 0.f, 0.f};
            s_ = __builtin_amdgcn_mfma_f32_16x16x32_bf16(aq[rf][0], kf[c][0], s_, 0, 0, 0);
            s_ = __builtin_amdgcn_mfma_f32_16x16x32_bf16(aq[rf][1], kf[c][1], s_, 0, 0, 0);
            sc[rf][c] = s_;
          }
      }

      // ---- softmax (Q pre-scaled -> bare exp2) + swizzled P write ----
#pragma unroll
      for (int rf = 0; rf < 2; ++rf) {
        const bool doMask = causal && (kv0 + 63 > rowb0 + rf * 16);
#pragma unroll
        for (int r = 0; r < 4; ++r) {
          const int rowg = rowb0 + rf * 16 + quad * 4 + r;
          float p[4];
#pragma unroll
          for (int c = 0; c < 4; ++c) {
            float e = sc[rf][c][r];
            if (doMask && (kv0 + c * 16 + ln > rowg)) e = NEG_BIG;
            p[c] = exp2f(e);
          }
          l_r[rf][r] += (p[0] + p[1]) + (p[2] + p[3]);
          const int m = rf * 16 + quad * 4 + r;
          __bf16* pr = ptw + m * 64;
#pragma unroll
          for (int c = 0; c < 4; ++c) {
            const int col = c * 16 + ln;
            pr[(((col >> 3) ^ (m & 7)) << 3) + (col & 7)] = (__bf16)p[c];
          }
        }
      }
      __asm__ volatile("s_waitcnt lgkmcnt(0)" ::: "memory");
      __builtin_amdgcn_sched_barrier(0);

      // ---- PV: 16 MFMA, swizzled P / V reads ----
      {
        bf16x8 pa[2][2];
#pragma unroll
        for (int rf = 0; rf < 2; ++rf) {
          const int m = rf * 16 + ln;
#pragma unroll
          for (int ks = 0; ks < 2; ++ks)
            pa[rf][ks] = *(const bf16x8*)(ptw + m * 64 + (((ks * 4 + quad) ^ (m & 7)) * 8));
        }
#pragma unroll
        for (int nb = 0; nb < 4; ++nb) {
          const int vrow = nb * 16 + ln;
          const bf16x8 vf0 = *(const bf16x8*)(vv + vrow * 64 + (((quad)     ^ (ln & 7)) * 8));
          const bf16x8 vf1 = *(const bf16x8*)(vv + vrow * 64 + (((4 + quad) ^ (ln & 7)) * 8));
#pragma unroll
          for (int rf = 0; rf < 2; ++rf) {
            acc[rf][nb] = __builtin_amdgcn_mfma_f32_16x16x32_bf16(pa[rf][0], vf0, acc[rf][nb], 0, 0, 0);
            acc[rf][nb] = __builtin_amdgcn_mfma_f32_16x16x32_bf16(pa[rf][1], vf1, acc[rf][nb], 0, 0, 0);
          }
        }
      }
    }

    __asm__ volatile("" ::: "memory");
    __builtin_amdgcn_sched_barrier(0);
    __builtin_amdgcn_s_barrier();              // buf[cur] free for next stage
  }

  // ---- finalize: row-sum over the 16 lanes of each ln group ----
#pragma unroll
  for (int rf = 0; rf < 2; ++rf) {
#pragma unroll
    for (int r = 0; r < 4; ++r) {
      float l = l_r[rf][r];
#pragma unroll
      for (int off = 1; off < 16; off <<= 1) l += __shfl_xor(l, off, 64);
      const float inv = 1.f / fmaxf(l, 1e-30f);
      const int rowg = rowb0 + rf * 16 + quad * 4 + r;
      __bf16* op = outp + (size_t)(b * SS + rowg) * DD + h * 64;
#pragma unroll
      for (int nb = 0; nb < 4; ++nb)
        op[nb * 16 + ln] = (__bf16)sanit(acc[rf][nb][r] * inv);
    }
  }
}

// ============================================================
// LayerNorm rows of 1024 (unchanged)
// ============================================================
__global__ __launch_bounds__(256) void ln_k(
    const float* __restrict__ residf, const float* __restrict__ proj,
    const float* __restrict__ g, const float* __restrict__ be,
    float* __restrict__ outf, __bf16* __restrict__ outb)
{
  const int row = blockIdx.x, tid = threadIdx.x;
  const f32x4 pb = ((const f32x4*)(proj   + (size_t)row * 1024))[tid];
  const f32x4 rb = ((const f32x4*)(residf + (size_t)row * 1024))[tid];
  f32x4 x;
#pragma unroll
  for (int i = 0; i < 4; i++)
    x[i] = fminf(fmaxf(pb[i] + rb[i], -1e15f), 1e15f);
  float s  = x[0] + x[1] + x[2] + x[3];
  float ss = x[0]*x[0] + x[1]*x[1] + x[2]*x[2] + x[3]*x[3];
#pragma unroll
  for (int off = 1; off < 64; off <<= 1) {
    s  += __shfl_xor(s,  off, 64);
    ss += __shfl_xor(ss, off, 64);
  }
  __shared__ float sm[8];
  if ((tid & 63) == 0) { sm[tid >> 6] = s; sm[4 + (tid >> 6)] = ss; }
  __syncthreads();
  s  = sm[0] + sm[1] + sm[2] + sm[3];
  ss = sm[4] + sm[5] + sm[6] + sm[7];
  const float mean = s * (1.f / 1024.f);
  const float var  = fmaxf(ss * (1.f / 1024.f) - mean * mean, 0.f);
  const float rstd = rsqrtf(var + 1e-5f);
  const int c = tid * 4;
  f32x4 o;
#pragma unroll
  for (int i = 0; i < 4; i++)
    o[i] = g[c + i] * ((x[i] - mean) * rstd) + be[c + i];
  if (outf) ((f32x4*)(outf + (size_t)row * 1024))[tid] = o;
  if (outb) {
    bf16x4 ob;
#pragma unroll
    for (int i = 0; i < 4; i++) ob[i] = (__bf16)o[i];
    ((bf16x4*)(outb + (size_t)row * 1024))[tid] = ob;
  }
}

// ============================================================
extern "C" void kernel_launch(void* const* d_in, const int* in_sizes, int n_in,
                              void* d_out, int out_size, void* d_ws, size_t ws_size,
                              hipStream_t stream)
{
  const float* x      = (const float*)d_in[0];
  const float* enc    = (const float*)d_in[1];
  const float* w_qkv  = (const float*)d_in[2];
  const float* b_qkv  = (const float*)d_in[3];
  const float* w_sa_o = (const float*)d_in[4];
  const float* b_sa_o = (const float*)d_in[5];
  const float* w_q    = (const float*)d_in[6];
  const float* b_q    = (const float*)d_in[7];
  const float* w_k    = (const float*)d_in[8];
  const float* b_k    = (const float*)d_in[9];
  const float* w_v    = (const float*)d_in[10];
  const float* b_v    = (const float*)d_in[11];
  const float* w_ca_o = (const float*)d_in[12];
  const float* b_ca_o = (const float*)d_in[13];
  const float* w1     = (const float*)d_in[14];
  const float* b1     = (const float*)d_in[15];
  const float* w2     = (const float*)d_in[16];
  const float* b2     = (const float*)d_in[17];
  const float* g1     = (const float*)d_in[18];
  const float* be1    = (const float*)d_in[19];
  const float* g2     = (const float*)d_in[20];
  const float* be2    = (const float*)d_in[21];
  const float* g3     = (const float*)d_in[22];
  const float* be3    = (const float*)d_in[23];

  // ---- workspace layout, peak ~136 MB ----
  const size_t MB = 1024 * 1024;
  char* base = (char*)d_ws;
  __bf16* wqkvT = (__bf16*)(base + 0 * MB);
  __bf16* wsaoT = (__bf16*)(base + 6 * MB);
  __bf16* wqT   = (__bf16*)(base + 8 * MB);
  __bf16* wkT   = (__bf16*)(base + 10 * MB);
  __bf16* wvT   = (__bf16*)(base + 12 * MB);
  __bf16* wcaoT = (__bf16*)(base + 14 * MB);
  __bf16* w1T   = (__bf16*)(base + 0 * MB);    // overlays small weights, post-CA
  __bf16* w2T   = (__bf16*)(base + 8 * MB);
  __bf16* xb    = (__bf16*)(base + 16 * MB);
  __bf16* encb  = (__bf16*)(base + 24 * MB);
  __bf16* qkv   = (__bf16*)(base + 32 * MB);   // 24 MB
  __bf16* vt    = (__bf16*)(base + 56 * MB);   // 8 MB
  __bf16* mid   = (__bf16*)(base + 32 * MB);   // overlays qkv+vt in FFN phase
  __bf16* attnb = (__bf16*)(base + 64 * MB);
  float*  proj  = (float*) (base + 72 * MB);
  float*  h1f   = (float*) (base + 88 * MB);
  __bf16* h1b   = (__bf16*)(base + 104 * MB);
  float*  h2f   = (float*) (base + 112 * MB);
  __bf16* h2b   = (__bf16*)(base + 128 * MB);
  __bf16* qb = qkv;
  __bf16* kb = qkv + (size_t)MROWS * 1024;
  __bf16* vb = qkv + (size_t)MROWS * 2048;

  // ---- input converts + early weight transposes ----
  cvt_bf16<<<4096, 256, 0, stream>>>(x,   xb);
  cvt_bf16<<<4096, 256, 0, stream>>>(enc, encb);
  wtrans<<<dim3(48, 16), 256, 0, stream>>>(w_qkv,  wqkvT, 1024, 3072);
  wtrans<<<dim3(16, 16), 256, 0, stream>>>(w_sa_o, wsaoT, 1024, 1024);
  wtrans<<<dim3(16, 16), 256, 0, stream>>>(w_q,    wqT,   1024, 1024);
  wtrans<<<dim3(16, 16), 256, 0, stream>>>(w_k,    wkT,   1024, 1024);
  wtrans<<<dim3(16, 16), 256, 0, stream>>>(w_v,    wvT,   1024, 1024);
  wtrans<<<dim3(16, 16), 256, 0, stream>>>(w_ca_o, wcaoT, 1024, 1024);

  // ---- self-attention (Q pre-scaled by 0.125*log2e in MODE 3) ----
  gemm_bt<3><<<dim3(24, 32), 256, 0, stream>>>(xb, wqkvT, b_qkv, qkv, 3072, 1024);
  vtrans<<<dim3(16, 64), 256, 0, stream>>>(qkv, 3072, 192, 128, vt);
  attn<<<512, 256, 0, stream>>>(qkv, 3072, 192, 0,
                                qkv, 3072, 192, 64, vt, attnb, 1);
  gemm_bt64<2><<<dim3(16, 32), 256, 0, stream>>>(attnb, wsaoT, b_sa_o, proj, 1024, 1024);
  ln_k<<<4096, 256, 0, stream>>>(x, proj, g1, be1, h1f, h1b);

  // ---- cross-attention ----
  gemm_bt64<3><<<dim3(16, 32), 256, 0, stream>>>(h1b, wqT, b_q, qb, 1024, 1024);
  gemm_bt64<0><<<dim3(16, 32), 256, 0, stream>>>(encb, wkT, b_k, kb, 1024, 1024);
  gemm_bt64<0><<<dim3(16, 32), 256, 0, stream>>>(encb, wvT, b_v, vb, 1024, 1024);
  vtrans<<<dim3(16, 64), 256, 0, stream>>>(vb, 1024, 64, 0, vt);
  attn<<<512, 256, 0, stream>>>(qb, 1024, 64, 0,
                                kb, 1024, 64, 0, vt, attnb, 0);
  gemm_bt64<2><<<dim3(16, 32), 256, 0, stream>>>(attnb, wcaoT, b_ca_o, proj, 1024, 1024);
  ln_k<<<4096, 256, 0, stream>>>(h1f, proj, g2, be2, h2f, h2b);

  // ---- FFN ----
  wtrans<<<dim3(64, 16), 256, 0, stream>>>(w1, w1T, 1024, 4096);
  wtrans<<<dim3(16, 64), 256, 0, stream>>>(w2, w2T, 4096, 1024);
  gemm_bt<1><<<dim3(32, 32), 256, 0, stream>>>(h2b, w1T, b1, mid, 4096, 1024);
  gemm_bt64<2><<<dim3(16, 32), 256, 0, stream>>>(mid, w2T, b2, proj, 1024, 4096);
  ln_k<<<4096, 256, 0, stream>>>(h2f, proj, g3, be3, (float*)d_out, nullptr);

  (void)in_sizes; (void)n_in; (void)out_size; (void)ws_size;
}

// Round 4
// 572.037 us; speedup vs baseline: 1.2378x; 1.0448x over previous
//
#include <hip/hip_runtime.h>

// ---- problem constants ----
#define BB 4
#define SS 1024
#define DD 1024
#define HH 16
#define DHH 64
#define DFF 4096
#define MROWS 4096   // B*S
#define NEG_BIG (-1e30f)
#define LOG2E 1.4426950408889634f
#define SCL_L2E 0.1803368801111244f   // 0.125 * log2(e)

typedef float  f32x4  __attribute__((ext_vector_type(4)));
typedef __bf16 bf16x8 __attribute__((ext_vector_type(8)));
typedef __bf16 bf16x4 __attribute__((ext_vector_type(4)));

#define DEV __device__ __forceinline__

DEV void glds16(const __bf16* g, __bf16* l) {
  __builtin_amdgcn_global_load_lds((__attribute__((address_space(1))) void*)(g),
                                   (__attribute__((address_space(3))) void*)(l),
                                   16, 0, 0);
}

DEV float sanit(float v) {  // NaN/inf absorbing clamp
  return fminf(fmaxf(v, -1e30f), 1e30f);
}

// exact-GELU via A&S 7.1.26 erf (|err|<=1.5e-7, invisible at bf16).
DEV float gelu_f(float v) {
  const float z  = fabsf(v) * 0.70710678118654752f;
  const float t  = __builtin_amdgcn_rcpf(1.f + 0.3275911f * z);
  float poly = ((((1.061405429f * t - 1.453152027f) * t + 1.421413741f) * t
                 - 0.284496736f) * t + 0.254829592f) * t;
  float er = 1.f - poly * __expf(-z * z);
  er = copysignf(er, v);
  return 0.5f * v * (1.f + er);
}

// ============================================================
// f32 -> bf16 elementwise convert (4 elems/thread)
// ============================================================
__global__ __launch_bounds__(256) void cvt_bf16(const float* __restrict__ src,
                                                __bf16* __restrict__ dst)
{
  const int idx = blockIdx.x * 256 + threadIdx.x;
  const f32x4 v = ((const f32x4*)src)[idx];
  bf16x4 o;
#pragma unroll
  for (int i = 0; i < 4; i++) o[i] = (__bf16)v[i];
  ((bf16x4*)dst)[idx] = o;
}

// ============================================================
// LDS-tiled transpose+convert: src f32 [K][N] -> dst bf16 [N][K]
// ============================================================
__global__ __launch_bounds__(256) void wtrans(const float* __restrict__ src,
                                              __bf16* __restrict__ dst,
                                              int K, int N)
{
  __shared__ float t[64][65];
  const int k0 = blockIdx.y * 64, n0 = blockIdx.x * 64;
  const int c = threadIdx.x & 63, r0 = threadIdx.x >> 6;
#pragma unroll
  for (int i = 0; i < 16; i++) {
    const int r = r0 * 16 + i;
    t[r][c] = src[(size_t)(k0 + r) * N + n0 + c];
  }
  __syncthreads();
#pragma unroll
  for (int i = 0; i < 16; i++) {
    const int r = r0 * 16 + i;
    dst[(size_t)(n0 + r) * K + k0 + c] = (__bf16)t[c][r];
  }
}

// ============================================================
// LDS-tiled V transpose (bf16): dst[bh][d][s]
// ============================================================
__global__ __launch_bounds__(256) void vtrans(const __bf16* __restrict__ src,
                                              int stride, int colMul, int colAdd,
                                              __bf16* __restrict__ dst)
{
  __shared__ __bf16 t[64][66];
  const int bh = blockIdx.y, b = bh >> 4, h = bh & 15;
  const int s0 = blockIdx.x * 64;
  const int c = threadIdx.x & 63, r0 = threadIdx.x >> 6;
  const __bf16* sp = src + (size_t)(b * SS) * stride + h * colMul + colAdd;
#pragma unroll
  for (int i = 0; i < 16; i++) {
    const int s = r0 * 16 + i;
    t[s][c] = sp[(size_t)(s0 + s) * stride + c];
  }
  __syncthreads();
  __bf16* dp = dst + (size_t)bh * 64 * 1024;
#pragma unroll
  for (int i = 0; i < 16; i++) {
    const int d = r0 * 16 + i;
    dp[(size_t)d * 1024 + s0 + c] = t[c][d];
  }
}

// ============================================================
// GEMM 128x128, 2-phase double-buffered.
// MODE 0: bf16 out; 1: gelu->bf16; 2: f32 out;
// MODE 3: bf16 out, scale Q-cols of fused qkv ((col%192)<64) by SCL_L2E
// MODE 4: bf16 out, dual bias (col<1024 -> bias, else bias2) for merged KV
// ============================================================
template<int MODE>
__global__ __launch_bounds__(256) void gemm_bt(
    const __bf16* __restrict__ A, const __bf16* __restrict__ Bt,
    const float* __restrict__ bias, const float* __restrict__ bias2,
    void* __restrict__ Cout, int N, int K)
{
  __shared__ __align__(16) __bf16 As[2][128 * 32];
  __shared__ __align__(16) __bf16 Bs[2][128 * 32];

  const int bm = blockIdx.y * 128, bn = blockIdx.x * 128;
  const int tid = threadIdx.x, wid = tid >> 6, lane = tid & 63;
  const int quad = lane >> 4, ln = lane & 15;

  const __bf16* gA = A  + (size_t)(bm + wid * 32 + (lane >> 2)) * K + (lane & 3) * 8;
  const __bf16* gB = Bt + (size_t)(bn + wid * 32 + (lane >> 2)) * K + (lane & 3) * 8;
  const int soff = (wid * 32) * 32;

  f32x4 acc[4][4];
#pragma unroll
  for (int i = 0; i < 4; i++)
#pragma unroll
    for (int j = 0; j < 4; j++) acc[i][j] = (f32x4){0.f, 0.f, 0.f, 0.f};

  const int wr = (wid >> 1) * 64, wc = (wid & 1) * 64;

#define G_STAGE(buf, kt) do {                                     \
    const int k0_ = (kt) * 32;                                    \
    glds16(gA + k0_,          &As[buf][soff]);                    \
    glds16(gA + 16 * K + k0_, &As[buf][soff + 16 * 32]);          \
    glds16(gB + k0_,          &Bs[buf][soff]);                    \
    glds16(gB + 16 * K + k0_, &Bs[buf][soff + 16 * 32]);          \
  } while (0)

#define G_COMP(buf) do {                                                    \
    bf16x8 af[4], bfr[4];                                                   \
    _Pragma("unroll")                                                       \
    for (int i = 0; i < 4; i++)                                             \
      af[i] = *(const bf16x8*)(&As[buf][(wr + i * 16 + ln) * 32 + quad * 8]); \
    _Pragma("unroll")                                                       \
    for (int j = 0; j < 4; j++)                                             \
      bfr[j] = *(const bf16x8*)(&Bs[buf][(wc + j * 16 + ln) * 32 + quad * 8]); \
    _Pragma("unroll")                                                       \
    for (int i = 0; i < 4; i++)                                             \
      _Pragma("unroll")                                                     \
      for (int j = 0; j < 4; j++)                                           \
        acc[i][j] = __builtin_amdgcn_mfma_f32_16x16x32_bf16(af[i], bfr[j], acc[i][j], 0, 0, 0); \
  } while (0)

  const int nk = K >> 5;              // K-steps of 32; K%64==0 -> nk even
  G_STAGE(0, 0);
  __syncthreads();
  for (int kt = 0; kt < nk; kt += 2) {
    G_STAGE(1, kt + 1);               // prefetch next tile
    G_COMP(0);
    __syncthreads();                  // vmcnt(0)+barrier: tile kt+1 landed
    if (kt + 2 < nk) G_STAGE(0, kt + 2);
    G_COMP(1);
    __syncthreads();
  }
#undef G_STAGE
#undef G_COMP

#pragma unroll
  for (int j = 0; j < 4; j++) {
    const int col = bn + wc + j * 16 + ln;
    float bv;
    if (MODE == 4) bv = (col < 1024) ? bias[col] : bias2[col - 1024];
    else           bv = bias[col];
#pragma unroll
    for (int i = 0; i < 4; i++) {
#pragma unroll
      for (int r = 0; r < 4; r++) {
        const int row = bm + wr + i * 16 + quad * 4 + r;
        float v = sanit(acc[i][j][r] + bv);
        if (MODE == 1) v = gelu_f(v);
        if (MODE == 3 && (col % 192) < 64) v *= SCL_L2E;
        if (MODE == 2) ((float*)Cout)[(size_t)row * N + col] = v;
        else           ((__bf16*)Cout)[(size_t)row * N + col] = (__bf16)v;
      }
    }
  }
}

// ============================================================
// GEMM 128x64, 2-phase double-buffered — for N=1024 shapes.
// MODE 0: bf16; 2: f32; 3: bf16 scaled by SCL_L2E (cross-attn Q)
// SPLIT=1: split-K over blockIdx.z (2 halves); z-th partial written to
// Cout + z*MROWS*N (f32); bias added only by z==0. Consumer sums.
// ============================================================
template<int MODE, int SPLIT>
__global__ __launch_bounds__(256) void gemm_bt64(
    const __bf16* __restrict__ A, const __bf16* __restrict__ Bt,
    const float* __restrict__ bias, void* __restrict__ Cout,
    int N, int K)
{
  __shared__ __align__(16) __bf16 As[2][128 * 32];
  __shared__ __align__(16) __bf16 Bs[2][64 * 32];

  const int bm = blockIdx.y * 128, bn = blockIdx.x * 64;
  const int kz = SPLIT ? blockIdx.z : 0;
  const int kOff = SPLIT ? kz * (K >> 1) : 0;
  const int tid = threadIdx.x, wid = tid >> 6, lane = tid & 63;
  const int quad = lane >> 4, ln = lane & 15;

  const __bf16* gA = A  + (size_t)(bm + wid * 32 + (lane >> 2)) * K + (lane & 3) * 8 + kOff;
  const __bf16* gB = Bt + (size_t)(bn + wid * 16 + (lane >> 2)) * K + (lane & 3) * 8 + kOff;
  const int aoff = (wid * 32) * 32;
  const int boff = (wid * 16) * 32;

  f32x4 acc[4][2];
#pragma unroll
  for (int i = 0; i < 4; i++)
#pragma unroll
    for (int j = 0; j < 2; j++) acc[i][j] = (f32x4){0.f, 0.f, 0.f, 0.f};

  const int wr = (wid >> 1) * 64, wc = (wid & 1) * 32;

#define G_STAGE(buf, kt) do {                                     \
    const int k0_ = (kt) * 32;                                    \
    glds16(gA + k0_,          &As[buf][aoff]);                    \
    glds16(gA + 16 * K + k0_, &As[buf][aoff + 16 * 32]);          \
    glds16(gB + k0_,          &Bs[buf][boff]);                    \
  } while (0)

#define G_COMP(buf) do {                                                    \
    bf16x8 af[4], bfr[2];                                                   \
    _Pragma("unroll")                                                       \
    for (int i = 0; i < 4; i++)                                             \
      af[i] = *(const bf16x8*)(&As[buf][(wr + i * 16 + ln) * 32 + quad * 8]); \
    _Pragma("unroll")                                                       \
    for (int j = 0; j < 2; j++)                                             \
      bfr[j] = *(const bf16x8*)(&Bs[buf][(wc + j * 16 + ln) * 32 + quad * 8]); \
    _Pragma("unroll")                                                       \
    for (int i = 0; i < 4; i++)                                             \
      _Pragma("unroll")                                                     \
      for (int j = 0; j < 2; j++)                                           \
        acc[i][j] = __builtin_amdgcn_mfma_f32_16x16x32_bf16(af[i], bfr[j], acc[i][j], 0, 0, 0); \
  } while (0)

  const int nk = (K >> SPLIT) >> 5;
  G_STAGE(0, 0);
  __syncthreads();
  for (int kt = 0; kt < nk; kt += 2) {
    G_STAGE(1, kt + 1);
    G_COMP(0);
    __syncthreads();
    if (kt + 2 < nk) G_STAGE(0, kt + 2);
    G_COMP(1);
    __syncthreads();
  }
#undef G_STAGE
#undef G_COMP

  float* outF = (float*)Cout + (SPLIT ? (size_t)kz * MROWS * N : 0);
#pragma unroll
  for (int j = 0; j < 2; j++) {
    const int col = bn + wc + j * 16 + ln;
    const float bv = (SPLIT && kz) ? 0.f : bias[col];
#pragma unroll
    for (int i = 0; i < 4; i++) {
#pragma unroll
      for (int r = 0; r < 4; r++) {
        const int row = bm + wr + i * 16 + quad * 4 + r;
        float v = sanit(acc[i][j][r] + bv);
        if (MODE == 3) v *= SCL_L2E;
        if (MODE == 2) outF[(size_t)row * N + col] = v;
        else           ((__bf16*)Cout)[(size_t)row * N + col] = (__bf16)v;
      }
    }
  }
}

// ============================================================
// Flash attention (unchanged from round 2's passing version).
// grid = 512; block 256. LDS 48 KB.
// ============================================================
__global__ __launch_bounds__(256) void attn(
    const __bf16* __restrict__ qp, int qStride, int qMul, int qAdd,
    const __bf16* __restrict__ kp, int kStride, int kMul, int kAdd,
    const __bf16* __restrict__ vt, __bf16* __restrict__ outp, int causal)
{
  __shared__ __align__(16) __bf16 Kt[2][64 * 64];   // [buf][row][64] swizzled
  __shared__ __align__(16) __bf16 Vt[2][64 * 64];   // [buf][dh][64]  swizzled
  __shared__ __align__(16) __bf16 ptl[4][32 * 64];  // per-wave P, swizzled

  const int id = blockIdx.x;
  const int bh = ((id >> 6) << 3) | (id & 7);       // keep bh%8 == id%8 (XCD)
  const int qblk = (id >> 3) & 7;
  const int b = bh >> 4, h = bh & 15;
  const int tid = threadIdx.x, wid = tid >> 6, lane = tid & 63;
  const int quad = lane >> 4, ln = lane & 15;
  const int qbase = qblk * 128;
  const int rowb0 = qbase + wid * 32;               // wave's first Q row
  const int rowTop = rowb0 + 31;

  // ---- Q fragments in registers: A[m=ln][k=quad*8+j] ----
  bf16x8 aq[2][2];
#pragma unroll
  for (int rf = 0; rf < 2; ++rf) {
    const __bf16* qr = qp + (size_t)(b * SS + rowb0 + rf * 16 + ln) * qStride
                          + h * qMul + qAdd;
#pragma unroll
    for (int ks = 0; ks < 2; ++ks)
      aq[rf][ks] = *(const bf16x8*)(qr + ks * 32 + quad * 8);
  }

  f32x4 acc[2][4];
#pragma unroll
  for (int rf = 0; rf < 2; ++rf)
#pragma unroll
    for (int nb = 0; nb < 4; ++nb) acc[rf][nb] = (f32x4){0.f, 0.f, 0.f, 0.f};
  float l_r[2][4] = {{0.f,0.f,0.f,0.f},{0.f,0.f,0.f,0.f}};

  const __bf16* kbase = kp + (size_t)(b * SS) * kStride + h * kMul + kAdd;
  const __bf16* vtb = vt + (size_t)bh * 64 * 1024;
  __bf16* ptw = ptl[wid];

  const int kvEnd = causal ? (qbase + 128) : SS;
  const int nT = kvEnd >> 6;

  // staging geometry: lane covers linear LDS row r = wave_quarter + lane/8,
  // 16B granule q = lane%8. Global source pre-swizzled: granule q holds
  // global granule q^(r&7)  (rule #21: linear dest + inv-swz source).
  const int sr = wid * 16 + (lane >> 3);   // +8 for p=1
  const int sq = lane & 7;

  // prologue: stage tile 0
#pragma unroll
  for (int p = 0; p < 2; ++p) {
    const int r = sr + p * 8;
    const int qs = (sq ^ (r & 7)) * 8;
    glds16(kbase + (size_t)r * kStride + qs, Kt[0] + (wid * 2 + p) * 512);
    glds16(vtb + (size_t)r * 1024 + qs,      Vt[0] + (wid * 2 + p) * 512);
  }

  for (int t = 0; t < nT; ++t) {
    const int cur = t & 1;
    const int kv0 = t * 64;

    if (t + 1 < nT) {
      const int kn = kv0 + 64;
#pragma unroll
      for (int p = 0; p < 2; ++p) {
        const int r = sr + p * 8;
        const int qs = (sq ^ (r & 7)) * 8;
        glds16(kbase + (size_t)(kn + r) * kStride + qs, Kt[cur ^ 1] + (wid * 2 + p) * 512);
        glds16(vtb + (size_t)r * 1024 + kn + qs,        Vt[cur ^ 1] + (wid * 2 + p) * 512);
      }
      __asm__ volatile("s_waitcnt vmcnt(4)" ::: "memory");  // tile t landed (mine)
    } else {
      __asm__ volatile("s_waitcnt vmcnt(0)" ::: "memory");
    }
    __builtin_amdgcn_sched_barrier(0);
    __builtin_amdgcn_s_barrier();              // everyone's quarter landed
    __asm__ volatile("" ::: "memory");
    __builtin_amdgcn_sched_barrier(0);

    if (!causal || kv0 <= rowTop) {
      const __bf16* kt = Kt[cur];
      const __bf16* vv = Vt[cur];

      // ---- QK^T: 16 MFMA, swizzled K reads ----
      f32x4 sc[2][4];
      {
        bf16x8 kf[4][2];
#pragma unroll
        for (int c = 0; c < 4; ++c) {
          const int row = c * 16 + ln;
#pragma unroll
          for (int ks = 0; ks < 2; ++ks)
            kf[c][ks] = *(const bf16x8*)(kt + row * 64 + (((ks * 4 + quad) ^ (ln & 7)) * 8));
        }
#pragma unroll
        for (int rf = 0; rf < 2; ++rf)
#pragma unroll
          for (int c = 0; c < 4; ++c) {
            f32x4 s_ = (f32x4){0.f, 0.f, 0.f, 0.f};
            s_ = __builtin_amdgcn_mfma_f32_16x16x32_bf16(aq[rf][0], kf[c][0], s_, 0, 0, 0);
            s_ = __builtin_amdgcn_mfma_f32_16x16x32_bf16(aq[rf][1], kf[c][1], s_, 0, 0, 0);
            sc[rf][c] = s_;
          }
      }

      // ---- softmax (Q pre-scaled -> bare exp2) + swizzled P write ----
#pragma unroll
      for (int rf = 0; rf < 2; ++rf) {
        const bool doMask = causal && (kv0 + 63 > rowb0 + rf * 16);
#pragma unroll
        for (int r = 0; r < 4; ++r) {
          const int rowg = rowb0 + rf * 16 + quad * 4 + r;
          float p[4];
#pragma unroll
          for (int c = 0; c < 4; ++c) {
            float e = sc[rf][c][r];
            if (doMask && (kv0 + c * 16 + ln > rowg)) e = NEG_BIG;
            p[c] = exp2f(e);
          }
          l_r[rf][r] += (p[0] + p[1]) + (p[2] + p[3]);
          const int m = rf * 16 + quad * 4 + r;
          __bf16* pr = ptw + m * 64;
#pragma unroll
          for (int c = 0; c < 4; ++c) {
            const int col = c * 16 + ln;
            pr[(((col >> 3) ^ (m & 7)) << 3) + (col & 7)] = (__bf16)p[c];
          }
        }
      }
      __asm__ volatile("s_waitcnt lgkmcnt(0)" ::: "memory");
      __builtin_amdgcn_sched_barrier(0);

      // ---- PV: 16 MFMA, swizzled P / V reads ----
      {
        bf16x8 pa[2][2];
#pragma unroll
        for (int rf = 0; rf < 2; ++rf) {
          const int m = rf * 16 + ln;
#pragma unroll
          for (int ks = 0; ks < 2; ++ks)
            pa[rf][ks] = *(const bf16x8*)(ptw + m * 64 + (((ks * 4 + quad) ^ (m & 7)) * 8));
        }
#pragma unroll
        for (int nb = 0; nb < 4; ++nb) {
          const int vrow = nb * 16 + ln;
          const bf16x8 vf0 = *(const bf16x8*)(vv + vrow * 64 + (((quad)     ^ (ln & 7)) * 8));
          const bf16x8 vf1 = *(const bf16x8*)(vv + vrow * 64 + (((4 + quad) ^ (ln & 7)) * 8));
#pragma unroll
          for (int rf = 0; rf < 2; ++rf) {
            acc[rf][nb] = __builtin_amdgcn_mfma_f32_16x16x32_bf16(pa[rf][0], vf0, acc[rf][nb], 0, 0, 0);
            acc[rf][nb] = __builtin_amdgcn_mfma_f32_16x16x32_bf16(pa[rf][1], vf1, acc[rf][nb], 0, 0, 0);
          }
        }
      }
    }

    __asm__ volatile("" ::: "memory");
    __builtin_amdgcn_sched_barrier(0);
    __builtin_amdgcn_s_barrier();              // buf[cur] free for next stage
  }

  // ---- finalize: row-sum over the 16 lanes of each ln group ----
#pragma unroll
  for (int rf = 0; rf < 2; ++rf) {
#pragma unroll
    for (int r = 0; r < 4; ++r) {
      float l = l_r[rf][r];
#pragma unroll
      for (int off = 1; off < 16; off <<= 1) l += __shfl_xor(l, off, 64);
      const float inv = 1.f / fmaxf(l, 1e-30f);
      const int rowg = rowb0 + rf * 16 + quad * 4 + r;
      __bf16* op = outp + (size_t)(b * SS + rowg) * DD + h * 64;
#pragma unroll
      for (int nb = 0; nb < 4; ++nb)
        op[nb * 16 + ln] = (__bf16)sanit(acc[rf][nb][r] * inv);
    }
  }
}

// ============================================================
// LayerNorm rows of 1024; optional second projection partial
// (split-K GEMM reduction folded in: x = resid + proj + proj2)
// ============================================================
__global__ __launch_bounds__(256) void ln_k(
    const float* __restrict__ residf, const float* __restrict__ proj,
    const float* __restrict__ proj2,
    const float* __restrict__ g, const float* __restrict__ be,
    float* __restrict__ outf, __bf16* __restrict__ outb)
{
  const int row = blockIdx.x, tid = threadIdx.x;
  const f32x4 pb = ((const f32x4*)(proj   + (size_t)row * 1024))[tid];
  const f32x4 rb = ((const f32x4*)(residf + (size_t)row * 1024))[tid];
  f32x4 x;
#pragma unroll
  for (int i = 0; i < 4; i++) x[i] = pb[i] + rb[i];
  if (proj2) {
    const f32x4 qb_ = ((const f32x4*)(proj2 + (size_t)row * 1024))[tid];
#pragma unroll
    for (int i = 0; i < 4; i++) x[i] += qb_[i];
  }
#pragma unroll
  for (int i = 0; i < 4; i++)
    x[i] = fminf(fmaxf(x[i], -1e15f), 1e15f);
  float s  = x[0] + x[1] + x[2] + x[3];
  float ss = x[0]*x[0] + x[1]*x[1] + x[2]*x[2] + x[3]*x[3];
#pragma unroll
  for (int off = 1; off < 64; off <<= 1) {
    s  += __shfl_xor(s,  off, 64);
    ss += __shfl_xor(ss, off, 64);
  }
  __shared__ float sm[8];
  if ((tid & 63) == 0) { sm[tid >> 6] = s; sm[4 + (tid >> 6)] = ss; }
  __syncthreads();
  s  = sm[0] + sm[1] + sm[2] + sm[3];
  ss = sm[4] + sm[5] + sm[6] + sm[7];
  const float mean = s * (1.f / 1024.f);
  const float var  = fmaxf(ss * (1.f / 1024.f) - mean * mean, 0.f);
  const float rstd = rsqrtf(var + 1e-5f);
  const int c = tid * 4;
  f32x4 o;
#pragma unroll
  for (int i = 0; i < 4; i++)
    o[i] = g[c + i] * ((x[i] - mean) * rstd) + be[c + i];
  if (outf) ((f32x4*)(outf + (size_t)row * 1024))[tid] = o;
  if (outb) {
    bf16x4 ob;
#pragma unroll
    for (int i = 0; i < 4; i++) ob[i] = (__bf16)o[i];
    ((bf16x4*)(outb + (size_t)row * 1024))[tid] = ob;
  }
}

// ============================================================
extern "C" void kernel_launch(void* const* d_in, const int* in_sizes, int n_in,
                              void* d_out, int out_size, void* d_ws, size_t ws_size,
                              hipStream_t stream)
{
  const float* x      = (const float*)d_in[0];
  const float* enc    = (const float*)d_in[1];
  const float* w_qkv  = (const float*)d_in[2];
  const float* b_qkv  = (const float*)d_in[3];
  const float* w_sa_o = (const float*)d_in[4];
  const float* b_sa_o = (const float*)d_in[5];
  const float* w_q    = (const float*)d_in[6];
  const float* b_q    = (const float*)d_in[7];
  const float* w_k    = (const float*)d_in[8];
  const float* b_k    = (const float*)d_in[9];
  const float* w_v    = (const float*)d_in[10];
  const float* b_v    = (const float*)d_in[11];
  const float* w_ca_o = (const float*)d_in[12];
  const float* b_ca_o = (const float*)d_in[13];
  const float* w1     = (const float*)d_in[14];
  const float* b1     = (const float*)d_in[15];
  const float* w2     = (const float*)d_in[16];
  const float* b2     = (const float*)d_in[17];
  const float* g1     = (const float*)d_in[18];
  const float* be1    = (const float*)d_in[19];
  const float* g2     = (const float*)d_in[20];
  const float* be2    = (const float*)d_in[21];
  const float* g3     = (const float*)d_in[22];
  const float* be3    = (const float*)d_in[23];

  // ---- workspace layout, peak ~136 MB ----
  const size_t MB = 1024 * 1024;
  char* base = (char*)d_ws;
  __bf16* wqkvT = (__bf16*)(base + 0 * MB);
  __bf16* wsaoT = (__bf16*)(base + 6 * MB);
  __bf16* wqT   = (__bf16*)(base + 8 * MB);
  __bf16* wkvT  = (__bf16*)(base + 10 * MB);   // wkT (10-12) + wvT (12-14) contiguous
  __bf16* wkT   = (__bf16*)(base + 10 * MB);
  __bf16* wvT   = (__bf16*)(base + 12 * MB);
  __bf16* wcaoT = (__bf16*)(base + 14 * MB);
  __bf16* w1T   = (__bf16*)(base + 0 * MB);    // overlays small weights, post-CA
  __bf16* w2T   = (__bf16*)(base + 8 * MB);
  __bf16* xb    = (__bf16*)(base + 16 * MB);
  __bf16* encb  = (__bf16*)(base + 24 * MB);
  __bf16* qkv   = (__bf16*)(base + 32 * MB);   // 24 MB (self-attn fused qkv)
  __bf16* kvb   = (__bf16*)(base + 32 * MB);   // CA merged K|V [4096][2048], 16 MB
  __bf16* qcab  = (__bf16*)(base + 48 * MB);   // CA Q [4096][1024], 8 MB
  __bf16* vt    = (__bf16*)(base + 56 * MB);   // 8 MB
  __bf16* mid   = (__bf16*)(base + 32 * MB);   // overlays, FFN phase (32 MB)
  __bf16* attnb = (__bf16*)(base + 64 * MB);
  float*  proj  = (float*) (base + 72 * MB);   // 16 MB
  float*  h1f   = (float*) (base + 88 * MB);   // 16 MB; reused as FFN2 partial z=1
  __bf16* h1b   = (__bf16*)(base + 104 * MB);
  float*  h2f   = (float*) (base + 112 * MB);
  __bf16* h2b   = (__bf16*)(base + 128 * MB);
  __bf16* qb = qkv;
  __bf16* kb = qkv + (size_t)MROWS * 1024;
  __bf16* vb = qkv + (size_t)MROWS * 2048;
  (void)kb; (void)vb; (void)wkT; (void)wvT;

  // ---- input converts + early weight transposes ----
  cvt_bf16<<<4096, 256, 0, stream>>>(x,   xb);
  cvt_bf16<<<4096, 256, 0, stream>>>(enc, encb);
  wtrans<<<dim3(48, 16), 256, 0, stream>>>(w_qkv,  wqkvT, 1024, 3072);
  wtrans<<<dim3(16, 16), 256, 0, stream>>>(w_sa_o, wsaoT, 1024, 1024);
  wtrans<<<dim3(16, 16), 256, 0, stream>>>(w_q,    wqT,   1024, 1024);
  wtrans<<<dim3(16, 16), 256, 0, stream>>>(w_k,    wkT,   1024, 1024);
  wtrans<<<dim3(16, 16), 256, 0, stream>>>(w_v,    wvT,   1024, 1024);
  wtrans<<<dim3(16, 16), 256, 0, stream>>>(w_ca_o, wcaoT, 1024, 1024);

  // ---- self-attention (Q pre-scaled by 0.125*log2e in MODE 3) ----
  gemm_bt<3><<<dim3(24, 32), 256, 0, stream>>>(xb, wqkvT, b_qkv, nullptr, qkv, 3072, 1024);
  vtrans<<<dim3(16, 64), 256, 0, stream>>>(qkv, 3072, 192, 128, vt);
  attn<<<512, 256, 0, stream>>>(qkv, 3072, 192, 0,
                                qkv, 3072, 192, 64, vt, attnb, 1);
  gemm_bt64<2,0><<<dim3(16, 32), 256, 0, stream>>>(attnb, wsaoT, b_sa_o, proj, 1024, 1024);
  ln_k<<<4096, 256, 0, stream>>>(x, proj, nullptr, g1, be1, h1f, h1b);

  // ---- cross-attention (K,V merged into one N=2048 GEMM) ----
  gemm_bt64<3,0><<<dim3(16, 32), 256, 0, stream>>>(h1b, wqT, b_q, qcab, 1024, 1024);
  gemm_bt<4><<<dim3(16, 32), 256, 0, stream>>>(encb, wkvT, b_k, b_v, kvb, 2048, 1024);
  vtrans<<<dim3(16, 64), 256, 0, stream>>>(kvb, 2048, 64, 1024, vt);
  attn<<<512, 256, 0, stream>>>(qcab, 1024, 64, 0,
                                kvb, 2048, 64, 0, vt, attnb, 0);
  gemm_bt64<2,0><<<dim3(16, 32), 256, 0, stream>>>(attnb, wcaoT, b_ca_o, proj, 1024, 1024);
  ln_k<<<4096, 256, 0, stream>>>(h1f, proj, nullptr, g2, be2, h2f, h2b);

  // ---- FFN (FFN2 split-K=2, partials summed inside final ln) ----
  wtrans<<<dim3(64, 16), 256, 0, stream>>>(w1, w1T, 1024, 4096);
  wtrans<<<dim3(16, 64), 256, 0, stream>>>(w2, w2T, 4096, 1024);
  gemm_bt<1><<<dim3(32, 32), 256, 0, stream>>>(h2b, w1T, b1, nullptr, mid, 4096, 1024);
  gemm_bt64<2,1><<<dim3(16, 32, 2), 256, 0, stream>>>(mid, w2T, b2, proj, 1024, 4096);
  ln_k<<<4096, 256, 0, stream>>>(h2f, proj, proj + (size_t)MROWS * 1024,
                                 g3, be3, (float*)d_out, nullptr);

  (void)in_sizes; (void)n_in; (void)out_size; (void)ws_size;
}